// Round 1
// baseline (5660.108 us; speedup 1.0000x reference)
//
#include <hip/hip_runtime.h>

#define F   128
#define FQ  32   // F/4

// ---------------------------------------------------------------------------
// Dense GEMM: H[n][f] = sum_k In[n][k] * W[k][f]
// If BN: input transformed as relu(a[k]*In[n][k] + c[k]) during LDS staging
// (BN is applied on the *input* of the second GEMM = output of first SpMM).
// Tile: 32 nodes x 128 features per block of 256 threads.
// LDS: full W (64 KB as float4) + transposed X tile (16 KB) -> 2 blocks/CU.
// ---------------------------------------------------------------------------
template <bool BN>
__global__ __launch_bounds__(256) void gemm_kernel(const float* __restrict__ X,
                                                   const float* __restrict__ W,
                                                   const float* __restrict__ ac,
                                                   float* __restrict__ H,
                                                   int nNodes) {
    __shared__ float4 wlds[F * FQ];   // wlds[k*32 + fq] = W[k][4fq .. 4fq+3]
    __shared__ float4 xt4[F * 8];     // xt[k*32 + n] = Xtile[n][k] (transposed)
    float* xt = (float*)xt4;

    const int tid = threadIdx.x;
    const int bn0 = blockIdx.x * 32;

    const float4* W4 = (const float4*)W;
    #pragma unroll
    for (int i = tid; i < F * FQ; i += 256) wlds[i] = W4[i];

    const float4* X4 = (const float4*)X;
    const float4* A4 = (const float4*)ac;        // a[f] scale
    const float4* C4 = (const float4*)(ac + F);  // c[f] shift
    for (int i = tid; i < 32 * FQ; i += 256) {
        int n = i >> 5;       // node within tile 0..31
        int kq = i & 31;      // feature quad 0..31
        int node = bn0 + n;
        float4 v = make_float4(0.f, 0.f, 0.f, 0.f);
        if (node < nNodes) v = X4[(size_t)node * FQ + kq];
        if (BN) {
            float4 a = A4[kq], c = C4[kq];
            v.x = fmaxf(fmaf(a.x, v.x, c.x), 0.f);
            v.y = fmaxf(fmaf(a.y, v.y, c.y), 0.f);
            v.z = fmaxf(fmaf(a.z, v.z, c.z), 0.f);
            v.w = fmaxf(fmaf(a.w, v.w, c.w), 0.f);
        }
        xt[(4 * kq + 0) * 32 + n] = v.x;
        xt[(4 * kq + 1) * 32 + n] = v.y;
        xt[(4 * kq + 2) * 32 + n] = v.z;
        xt[(4 * kq + 3) * 32 + n] = v.w;
    }
    __syncthreads();

    const int fq = tid & 31;   // feature quad  -> features 4fq..4fq+3
    const int ng = tid >> 5;   // node group 0..7 -> nodes 4ng..4ng+3

    float acc[4][4];
    #pragma unroll
    for (int i = 0; i < 4; ++i)
        #pragma unroll
        for (int j = 0; j < 4; ++j) acc[i][j] = 0.f;

    #pragma unroll 8
    for (int k = 0; k < F; ++k) {
        float4 wv = wlds[k * 32 + fq];
        float4 xv = xt4[k * 8 + ng];
        float xa[4] = {xv.x, xv.y, xv.z, xv.w};
        float wa[4] = {wv.x, wv.y, wv.z, wv.w};
        #pragma unroll
        for (int i = 0; i < 4; ++i)
            #pragma unroll
            for (int j = 0; j < 4; ++j)
                acc[i][j] = fmaf(xa[i], wa[j], acc[i][j]);
    }

    float4* H4 = (float4*)H;
    #pragma unroll
    for (int i = 0; i < 4; ++i) {
        int node = bn0 + 4 * ng + i;
        if (node < nNodes)
            H4[(size_t)node * FQ + fq] =
                make_float4(acc[i][0], acc[i][1], acc[i][2], acc[i][3]);
    }
}

// ---------------------------------------------------------------------------
// COO SpMM via atomics: Out[row[e]] += w[e] * H[col[e]]   (128 feats/edge)
// 32 consecutive lanes per edge, float4 gather (coalesced 512 B per edge).
// ---------------------------------------------------------------------------
__global__ __launch_bounds__(256) void spmm_kernel(const int* __restrict__ row,
                                                   const int* __restrict__ col,
                                                   const float* __restrict__ w,
                                                   const float* __restrict__ H,
                                                   float* __restrict__ out,
                                                   int nEdges) {
    long long t = (long long)blockIdx.x * 256 + threadIdx.x;
    int e = (int)(t >> 5);
    if (e >= nEdges) return;
    int l = (int)(t & 31);
    int r = row[e];
    int c = col[e];
    float wt = w[e];
    float4 v = ((const float4*)H)[(size_t)c * FQ + l];
    float* o = out + (size_t)r * F + l * 4;
    atomicAdd(o + 0, wt * v.x);
    atomicAdd(o + 1, wt * v.y);
    atomicAdd(o + 2, wt * v.z);
    atomicAdd(o + 3, wt * v.w);
}

// ---------------------------------------------------------------------------
// BN batch statistics: per-feature sum and sumsq over nodes.
// ---------------------------------------------------------------------------
__global__ __launch_bounds__(256) void bnstats_kernel(const float* __restrict__ H,
                                                      float* __restrict__ sums,
                                                      int nNodes) {
    int f = threadIdx.x & 127;
    int g = threadIdx.x >> 7;  // 0..1
    int stride = gridDim.x * 2;
    float s = 0.f, sq = 0.f;
    for (int n = blockIdx.x * 2 + g; n < nNodes; n += stride) {
        float v = H[(size_t)n * F + f];
        s += v;
        sq = fmaf(v, v, sq);
    }
    __shared__ float red[256];
    red[threadIdx.x] = s;
    __syncthreads();
    float sfull = 0.f;
    if (g == 0) sfull = red[f] + red[f + 128];
    __syncthreads();
    red[threadIdx.x] = sq;
    __syncthreads();
    if (g == 0) {
        float sqfull = red[f] + red[f + 128];
        atomicAdd(&sums[f], sfull);
        atomicAdd(&sums[128 + f], sqfull);
    }
}

// Fold mean/var/gamma/beta into per-feature scale a and shift c.
// Note: layer-1 bias b1 cancels exactly in BN (mean subtraction) -> unused.
__global__ void bnfinal_kernel(const float* __restrict__ sums,
                               const float* __restrict__ gamma,
                               const float* __restrict__ beta,
                               float* __restrict__ ac, float invN) {
    int f = threadIdx.x;
    float mean = sums[f] * invN;
    float var = sums[128 + f] * invN - mean * mean;
    float a = gamma[f] * rsqrtf(var + 1e-5f);
    ac[f] = a;
    ac[128 + f] = beta[f] - mean * a;
}

// out[n][f] = b2[f]  (bias pre-init so SpMM2 atomics produce spmm + b2)
__global__ __launch_bounds__(256) void initout_kernel(float* __restrict__ out,
                                                      const float* __restrict__ b2,
                                                      int total4) {
    int i = blockIdx.x * 256 + threadIdx.x;
    if (i < total4) ((float4*)out)[i] = ((const float4*)b2)[i & 31];
}

extern "C" void kernel_launch(void* const* d_in, const int* in_sizes, int n_in,
                              void* d_out, int out_size, void* d_ws, size_t ws_size,
                              hipStream_t stream) {
    const float* x    = (const float*)d_in[0];
    const int*   erow = (const int*)d_in[1];
    const int*   ecol = (const int*)d_in[2];
    const float* ew   = (const float*)d_in[3];
    const float* W1   = (const float*)d_in[4];
    // d_in[5] = b1: unused — cancels exactly under BatchNorm mean subtraction.
    const float* W2   = (const float*)d_in[6];
    const float* b2   = (const float*)d_in[7];
    const float* gmm  = (const float*)d_in[8];
    const float* beta = (const float*)d_in[9];
    float* out = (float*)d_out;

    const int N = in_sizes[0] / F;   // 100000
    const int E = in_sizes[1];       // 1600000

    float* buf0  = (float*)d_ws;                 // h0 (x@W1), later h2
    float* buf1  = buf0 + (size_t)N * F;         // h1 (spmm1 accumulator)
    float* stats = buf1 + (size_t)N * F;         // 256: sum, sumsq
    float* ac    = stats + 256;                  // 256: a, c

    // zero the atomic accumulators (ws is poisoned 0xAA before every launch)
    hipMemsetAsync(buf1, 0, (size_t)N * F * sizeof(float), stream);
    hipMemsetAsync(stats, 0, 256 * sizeof(float), stream);

    int gemmGrid = (N + 31) / 32;
    int spmmGrid = (int)(((long long)E * 32 + 255) / 256);

    // Layer 1: h0 = x @ W1
    gemm_kernel<false><<<gemmGrid, 256, 0, stream>>>(x, W1, nullptr, buf0, N);
    // h1 = A @ h0
    spmm_kernel<<<spmmGrid, 256, 0, stream>>>(erow, ecol, ew, buf0, buf1, E);
    // BN stats over h1
    bnstats_kernel<<<400, 256, 0, stream>>>(buf1, stats, N);
    bnfinal_kernel<<<1, 128, 0, stream>>>(stats, gmm, beta, ac, 1.0f / (float)N);
    // Layer 2: h2 = relu(bn(h1)) @ W2   (BN+ReLU fused into GEMM staging)
    gemm_kernel<true><<<gemmGrid, 256, 0, stream>>>(buf1, W2, ac, buf0, N);
    // out = b2; out += A @ h2
    initout_kernel<<<(N * FQ + 255) / 256, 256, 0, stream>>>(out, b2, N * FQ);
    spmm_kernel<<<spmmGrid, 256, 0, stream>>>(erow, ecol, ew, buf0, out, E);
}

// Round 2
// 794.509 us; speedup vs baseline: 7.1240x; 7.1240x over previous
//
#include <hip/hip_runtime.h>

#define F   128
#define FQ  32   // F/4
#define FH  64   // F/2

// ---------------------------------------------------------------------------
// Dense GEMM: H[n][f] = sum_k In[n][k] * W[k][f]
// If BN: input transformed as relu(a[k]*In[n][k] + c[k]) during LDS staging.
// Tile: 32 nodes x 128 features per block of 256 threads.
// LDS: full W (64 KB as float4) + transposed X tile (16 KB) -> 2 blocks/CU.
// ---------------------------------------------------------------------------
template <bool BN>
__global__ __launch_bounds__(256) void gemm_kernel(const float* __restrict__ X,
                                                   const float* __restrict__ W,
                                                   const float* __restrict__ ac,
                                                   float* __restrict__ H,
                                                   int nNodes) {
    __shared__ float4 wlds[F * FQ];   // wlds[k*32 + fq] = W[k][4fq .. 4fq+3]
    __shared__ float4 xt4[F * 8];     // xt[k*32 + n] = Xtile[n][k] (transposed)
    float* xt = (float*)xt4;

    const int tid = threadIdx.x;
    const int bn0 = blockIdx.x * 32;

    const float4* W4 = (const float4*)W;
    #pragma unroll
    for (int i = tid; i < F * FQ; i += 256) wlds[i] = W4[i];

    const float4* X4 = (const float4*)X;
    const float4* A4 = (const float4*)ac;        // a[f] scale
    const float4* C4 = (const float4*)(ac + F);  // c[f] shift
    for (int i = tid; i < 32 * FQ; i += 256) {
        int n = i >> 5;       // node within tile 0..31
        int kq = i & 31;      // feature quad 0..31
        int node = bn0 + n;
        float4 v = make_float4(0.f, 0.f, 0.f, 0.f);
        if (node < nNodes) v = X4[(size_t)node * FQ + kq];
        if (BN) {
            float4 a = A4[kq], c = C4[kq];
            v.x = fmaxf(fmaf(a.x, v.x, c.x), 0.f);
            v.y = fmaxf(fmaf(a.y, v.y, c.y), 0.f);
            v.z = fmaxf(fmaf(a.z, v.z, c.z), 0.f);
            v.w = fmaxf(fmaf(a.w, v.w, c.w), 0.f);
        }
        xt[(4 * kq + 0) * 32 + n] = v.x;
        xt[(4 * kq + 1) * 32 + n] = v.y;
        xt[(4 * kq + 2) * 32 + n] = v.z;
        xt[(4 * kq + 3) * 32 + n] = v.w;
    }
    __syncthreads();

    const int fq = tid & 31;   // feature quad  -> features 4fq..4fq+3
    const int ng = tid >> 5;   // node group 0..7 -> nodes 4ng..4ng+3

    float acc[4][4];
    #pragma unroll
    for (int i = 0; i < 4; ++i)
        #pragma unroll
        for (int j = 0; j < 4; ++j) acc[i][j] = 0.f;

    #pragma unroll 8
    for (int k = 0; k < F; ++k) {
        float4 wv = wlds[k * 32 + fq];
        float4 xv = xt4[k * 8 + ng];
        float xa[4] = {xv.x, xv.y, xv.z, xv.w};
        float wa[4] = {wv.x, wv.y, wv.z, wv.w};
        #pragma unroll
        for (int i = 0; i < 4; ++i)
            #pragma unroll
            for (int j = 0; j < 4; ++j)
                acc[i][j] = fmaf(xa[i], wa[j], acc[i][j]);
    }

    float4* H4 = (float4*)H;
    #pragma unroll
    for (int i = 0; i < 4; ++i) {
        int node = bn0 + 4 * ng + i;
        if (node < nNodes)
            H4[(size_t)node * FQ + fq] =
                make_float4(acc[i][0], acc[i][1], acc[i][2], acc[i][3]);
    }
}

// ---------------------------------------------------------------------------
// CSR build: count -> scan -> scatter
// ---------------------------------------------------------------------------
__global__ __launch_bounds__(256) void count_kernel(const int* __restrict__ row,
                                                    int* __restrict__ cnt, int E) {
    int e = blockIdx.x * 256 + threadIdx.x;
    if (e < E) atomicAdd(&cnt[row[e]], 1);
}

// Single-block exclusive prefix sum over N counts (chunks of 4096 = 1024 thr x 4).
__global__ __launch_bounds__(1024) void scan_kernel(const int* __restrict__ cnt,
                                                    int* __restrict__ rowptr,
                                                    int* __restrict__ wptr,
                                                    int N, int E) {
    __shared__ int wsum[16];
    __shared__ int carrySh;
    const int t = threadIdx.x;
    const int lane = t & 63, wv = t >> 6;
    if (t == 0) carrySh = 0;
    __syncthreads();
    for (int base = 0; base < N; base += 4096) {
        int i0 = base + t * 4;
        int v0 = (i0 + 0 < N) ? cnt[i0 + 0] : 0;
        int v1 = (i0 + 1 < N) ? cnt[i0 + 1] : 0;
        int v2 = (i0 + 2 < N) ? cnt[i0 + 2] : 0;
        int v3 = (i0 + 3 < N) ? cnt[i0 + 3] : 0;
        int s = v0 + v1 + v2 + v3;
        int inc = s;                       // wave inclusive scan of s
        #pragma unroll
        for (int off = 1; off < 64; off <<= 1) {
            int up = __shfl_up(inc, off, 64);
            if (lane >= off) inc += up;
        }
        if (lane == 63) wsum[wv] = inc;
        __syncthreads();
        int woff = 0;
        #pragma unroll
        for (int j = 0; j < 16; ++j) woff += (j < wv) ? wsum[j] : 0;
        int carry = carrySh;
        int excl = carry + woff + inc - s;  // exclusive offset of elem i0
        if (i0 + 0 < N) { rowptr[i0 + 0] = excl;             wptr[i0 + 0] = excl; }
        if (i0 + 1 < N) { rowptr[i0 + 1] = excl + v0;        wptr[i0 + 1] = excl + v0; }
        if (i0 + 2 < N) { rowptr[i0 + 2] = excl + v0 + v1;   wptr[i0 + 2] = excl + v0 + v1; }
        if (i0 + 3 < N) { rowptr[i0 + 3] = excl + v0 + v1 + v2; wptr[i0 + 3] = excl + v0 + v1 + v2; }
        __syncthreads();
        if (t == 1023) carrySh = carry + woff + inc;   // chunk total
        __syncthreads();
    }
    if (t == 0) rowptr[N] = E;
}

__global__ __launch_bounds__(256) void scatter_kernel(const int* __restrict__ row,
                                                      const int* __restrict__ col,
                                                      const float* __restrict__ w,
                                                      int* __restrict__ wptr,
                                                      int* __restrict__ colS,
                                                      float* __restrict__ wS, int E) {
    int e = blockIdx.x * 256 + threadIdx.x;
    if (e >= E) return;
    int pos = atomicAdd(&wptr[row[e]], 1);
    colS[pos] = col[e];
    wS[pos] = w[e];
}

// ---------------------------------------------------------------------------
// CSR SpMM: one wave per row, float2 per lane, register accumulate, 1 store.
// out[r] = (bias? bias : 0) + sum_i wS[i] * H[colS[i]]
// ---------------------------------------------------------------------------
__global__ __launch_bounds__(256) void spmm_csr_kernel(const int* __restrict__ rowptr,
                                                       const int* __restrict__ colS,
                                                       const float* __restrict__ wS,
                                                       const float* __restrict__ H,
                                                       const float* __restrict__ bias,
                                                       float* __restrict__ out, int N) {
    int r = blockIdx.x * 4 + (threadIdx.x >> 6);
    if (r >= N) return;
    int l = threadIdx.x & 63;
    const float2* H2 = (const float2*)H;
    float2 acc = bias ? ((const float2*)bias)[l] : make_float2(0.f, 0.f);
    int i = rowptr[r], end = rowptr[r + 1];
    for (; i + 1 < end; i += 2) {          // 2-edge unroll for MLP
        int c0 = colS[i], c1 = colS[i + 1];
        float w0 = wS[i], w1 = wS[i + 1];
        float2 v0 = H2[(size_t)c0 * FH + l];
        float2 v1 = H2[(size_t)c1 * FH + l];
        acc.x = fmaf(w0, v0.x, acc.x);
        acc.y = fmaf(w0, v0.y, acc.y);
        acc.x = fmaf(w1, v1.x, acc.x);
        acc.y = fmaf(w1, v1.y, acc.y);
    }
    if (i < end) {
        int c = colS[i];
        float wt = wS[i];
        float2 v = H2[(size_t)c * FH + l];
        acc.x = fmaf(wt, v.x, acc.x);
        acc.y = fmaf(wt, v.y, acc.y);
    }
    ((float2*)out)[(size_t)r * FH + l] = acc;
}

// ---------------------------------------------------------------------------
// Fallback (atomic) SpMM — used only if ws_size can't hold the CSR arrays.
// ---------------------------------------------------------------------------
__global__ __launch_bounds__(256) void spmm_kernel(const int* __restrict__ row,
                                                   const int* __restrict__ col,
                                                   const float* __restrict__ w,
                                                   const float* __restrict__ H,
                                                   float* __restrict__ out,
                                                   int nEdges) {
    long long t = (long long)blockIdx.x * 256 + threadIdx.x;
    int e = (int)(t >> 5);
    if (e >= nEdges) return;
    int l = (int)(t & 31);
    int r = row[e];
    int c = col[e];
    float wt = w[e];
    float4 v = ((const float4*)H)[(size_t)c * FQ + l];
    float* o = out + (size_t)r * F + l * 4;
    atomicAdd(o + 0, wt * v.x);
    atomicAdd(o + 1, wt * v.y);
    atomicAdd(o + 2, wt * v.z);
    atomicAdd(o + 3, wt * v.w);
}

// ---------------------------------------------------------------------------
// BN batch statistics: per-feature sum and sumsq over nodes.
// ---------------------------------------------------------------------------
__global__ __launch_bounds__(256) void bnstats_kernel(const float* __restrict__ H,
                                                      float* __restrict__ sums,
                                                      int nNodes) {
    int f = threadIdx.x & 127;
    int g = threadIdx.x >> 7;  // 0..1
    int stride = gridDim.x * 2;
    float s = 0.f, sq = 0.f;
    for (int n = blockIdx.x * 2 + g; n < nNodes; n += stride) {
        float v = H[(size_t)n * F + f];
        s += v;
        sq = fmaf(v, v, sq);
    }
    __shared__ float red[256];
    red[threadIdx.x] = s;
    __syncthreads();
    float sfull = 0.f;
    if (g == 0) sfull = red[f] + red[f + 128];
    __syncthreads();
    red[threadIdx.x] = sq;
    __syncthreads();
    if (g == 0) {
        float sqfull = red[f] + red[f + 128];
        atomicAdd(&sums[f], sfull);
        atomicAdd(&sums[128 + f], sqfull);
    }
}

// Fold mean/var/gamma/beta into per-feature scale a and shift c.
// Note: layer-1 bias b1 cancels exactly in BN (mean subtraction) -> unused.
__global__ void bnfinal_kernel(const float* __restrict__ sums,
                               const float* __restrict__ gamma,
                               const float* __restrict__ beta,
                               float* __restrict__ ac, float invN) {
    int f = threadIdx.x;
    float mean = sums[f] * invN;
    float var = sums[128 + f] * invN - mean * mean;
    float a = gamma[f] * rsqrtf(var + 1e-5f);
    ac[f] = a;
    ac[128 + f] = beta[f] - mean * a;
}

// out[n][f] = b2[f]  (fallback path only)
__global__ __launch_bounds__(256) void initout_kernel(float* __restrict__ out,
                                                      const float* __restrict__ b2,
                                                      int total4) {
    int i = blockIdx.x * 256 + threadIdx.x;
    if (i < total4) ((float4*)out)[i] = ((const float4*)b2)[i & 31];
}

extern "C" void kernel_launch(void* const* d_in, const int* in_sizes, int n_in,
                              void* d_out, int out_size, void* d_ws, size_t ws_size,
                              hipStream_t stream) {
    const float* x    = (const float*)d_in[0];
    const int*   erow = (const int*)d_in[1];
    const int*   ecol = (const int*)d_in[2];
    const float* ew   = (const float*)d_in[3];
    const float* W1   = (const float*)d_in[4];
    // d_in[5] = b1: unused — cancels exactly under BatchNorm mean subtraction.
    const float* W2   = (const float*)d_in[6];
    const float* b2   = (const float*)d_in[7];
    const float* gmm  = (const float*)d_in[8];
    const float* beta = (const float*)d_in[9];
    float* out = (float*)d_out;

    const int N = in_sizes[0] / F;   // 100000
    const int E = in_sizes[1];       // 1600000

    // ---- workspace carve-up ----
    float* buf0  = (float*)d_ws;                 // h0 (x@W1), later h2
    float* buf1  = buf0 + (size_t)N * F;         // h1 (spmm1 output)
    float* stats = buf1 + (size_t)N * F;         // 256: sum, sumsq
    float* ac    = stats + 256;                  // 256: a, c
    int*   cnt    = (int*)(ac + 256);            // N
    int*   rowptr = cnt + N;                     // N+1
    int*   wptr   = rowptr + N + 1;              // N
    int*   colS   = wptr + N;                    // E
    float* wS     = (float*)(colS + E);          // E
    size_t needed = (size_t)((char*)(wS + E) - (char*)d_ws);
    const bool useCsr = ws_size >= needed;

    const int gemmGrid = (N + 31) / 32;

    hipMemsetAsync(stats, 0, 256 * sizeof(float), stream);

    if (useCsr) {
        // ---- build CSR (shared by both SpMM layers) ----
        hipMemsetAsync(cnt, 0, (size_t)N * sizeof(int), stream);
        int eGrid = (E + 255) / 256;
        count_kernel<<<eGrid, 256, 0, stream>>>(erow, cnt, E);
        scan_kernel<<<1, 1024, 0, stream>>>(cnt, rowptr, wptr, N, E);
        scatter_kernel<<<eGrid, 256, 0, stream>>>(erow, ecol, ew, wptr, colS, wS, E);

        int spmmGrid = (N + 3) / 4;
        // Layer 1: h0 = x @ W1 ; h1 = A @ h0
        gemm_kernel<false><<<gemmGrid, 256, 0, stream>>>(x, W1, nullptr, buf0, N);
        spmm_csr_kernel<<<spmmGrid, 256, 0, stream>>>(rowptr, colS, wS, buf0,
                                                      nullptr, buf1, N);
        // BN stats + fold
        bnstats_kernel<<<400, 256, 0, stream>>>(buf1, stats, N);
        bnfinal_kernel<<<1, 128, 0, stream>>>(stats, gmm, beta, ac, 1.0f / (float)N);
        // Layer 2: h2 = relu(bn(h1)) @ W2 ; out = A @ h2 + b2
        gemm_kernel<true><<<gemmGrid, 256, 0, stream>>>(buf1, W2, ac, buf0, N);
        spmm_csr_kernel<<<spmmGrid, 256, 0, stream>>>(rowptr, colS, wS, buf0,
                                                      b2, out, N);
    } else {
        // ---- fallback: atomic scatter SpMM (round-1 baseline path) ----
        hipMemsetAsync(buf1, 0, (size_t)N * F * sizeof(float), stream);
        int spmmGrid = (int)(((long long)E * 32 + 255) / 256);
        gemm_kernel<false><<<gemmGrid, 256, 0, stream>>>(x, W1, nullptr, buf0, N);
        spmm_kernel<<<spmmGrid, 256, 0, stream>>>(erow, ecol, ew, buf0, buf1, E);
        bnstats_kernel<<<400, 256, 0, stream>>>(buf1, stats, N);
        bnfinal_kernel<<<1, 128, 0, stream>>>(stats, gmm, beta, ac, 1.0f / (float)N);
        gemm_kernel<true><<<gemmGrid, 256, 0, stream>>>(buf1, W2, ac, buf0, N);
        initout_kernel<<<(N * FQ + 255) / 256, 256, 0, stream>>>(out, b2, N * FQ);
        spmm_kernel<<<spmmGrid, 256, 0, stream>>>(erow, ecol, ew, buf0, out, E);
    }
}

// Round 3
// 618.472 us; speedup vs baseline: 9.1518x; 1.2846x over previous
//
#include <hip/hip_runtime.h>

#define F   128
#define FQ  32   // F/4 (float4 per row)
#define FU  64   // uints per bf16 row (128 bf16 = 64 uints)

// pack two fp32 -> two bf16 (RNE) in one uint (a = low = even feature)
__device__ __forceinline__ unsigned int f2bf2(float a, float b) {
    unsigned int ua = __float_as_uint(a);
    unsigned int ub = __float_as_uint(b);
    ua = (ua + 0x7fffu + ((ua >> 16) & 1u)) >> 16;
    ub = (ub + 0x7fffu + ((ub >> 16) & 1u)) >> 16;
    return ua | (ub << 16);
}

// ---------------------------------------------------------------------------
// Dense GEMM: H[n][f] = sum_k In[n][k] * W[k][f], output packed bf16.
// If BN: input transformed as relu(a[k]*In[n][k] + c[k]) during LDS staging.
// Tile: 32 nodes x 128 features per block of 256 threads.
// ---------------------------------------------------------------------------
template <bool BN>
__global__ __launch_bounds__(256) void gemm_kernel(const float* __restrict__ X,
                                                   const float* __restrict__ W,
                                                   const float* __restrict__ ac,
                                                   unsigned int* __restrict__ Hb,
                                                   int nNodes) {
    __shared__ float4 wlds[F * FQ];   // wlds[k*32 + fq] = W[k][4fq .. 4fq+3]
    __shared__ float4 xt4[F * 8];     // xt[k*32 + n] = Xtile[n][k] (transposed)
    float* xt = (float*)xt4;

    const int tid = threadIdx.x;
    const int bn0 = blockIdx.x * 32;

    const float4* W4 = (const float4*)W;
    #pragma unroll
    for (int i = tid; i < F * FQ; i += 256) wlds[i] = W4[i];

    const float4* X4 = (const float4*)X;
    const float4* A4 = (const float4*)ac;        // a[f] scale
    const float4* C4 = (const float4*)(ac + F);  // c[f] shift
    for (int i = tid; i < 32 * FQ; i += 256) {
        int n = i >> 5;       // node within tile 0..31
        int kq = i & 31;      // feature quad 0..31
        int node = bn0 + n;
        float4 v = make_float4(0.f, 0.f, 0.f, 0.f);
        if (node < nNodes) v = X4[(size_t)node * FQ + kq];
        if (BN) {
            float4 a = A4[kq], c = C4[kq];
            v.x = fmaxf(fmaf(a.x, v.x, c.x), 0.f);
            v.y = fmaxf(fmaf(a.y, v.y, c.y), 0.f);
            v.z = fmaxf(fmaf(a.z, v.z, c.z), 0.f);
            v.w = fmaxf(fmaf(a.w, v.w, c.w), 0.f);
        }
        xt[(4 * kq + 0) * 32 + n] = v.x;
        xt[(4 * kq + 1) * 32 + n] = v.y;
        xt[(4 * kq + 2) * 32 + n] = v.z;
        xt[(4 * kq + 3) * 32 + n] = v.w;
    }
    __syncthreads();

    const int fq = tid & 31;   // feature quad  -> features 4fq..4fq+3
    const int ng = tid >> 5;   // node group 0..7 -> nodes 4ng..4ng+3

    float acc[4][4];
    #pragma unroll
    for (int i = 0; i < 4; ++i)
        #pragma unroll
        for (int j = 0; j < 4; ++j) acc[i][j] = 0.f;

    #pragma unroll 8
    for (int k = 0; k < F; ++k) {
        float4 wv = wlds[k * 32 + fq];
        float4 xv = xt4[k * 8 + ng];
        float xa[4] = {xv.x, xv.y, xv.z, xv.w};
        float wa[4] = {wv.x, wv.y, wv.z, wv.w};
        #pragma unroll
        for (int i = 0; i < 4; ++i)
            #pragma unroll
            for (int j = 0; j < 4; ++j)
                acc[i][j] = fmaf(xa[i], wa[j], acc[i][j]);
    }

    uint2* H2 = (uint2*)Hb;   // row = 32 uint2
    #pragma unroll
    for (int i = 0; i < 4; ++i) {
        int node = bn0 + 4 * ng + i;
        if (node < nNodes)
            H2[(size_t)node * 32 + fq] =
                make_uint2(f2bf2(acc[i][0], acc[i][1]), f2bf2(acc[i][2], acc[i][3]));
    }
}

// ---------------------------------------------------------------------------
// CSR build: count -> 3-phase parallel scan -> scatter (packed int2 pairs)
// ---------------------------------------------------------------------------
__global__ __launch_bounds__(256) void count_kernel(const int* __restrict__ row,
                                                    int* __restrict__ cnt, int E) {
    int e = blockIdx.x * 256 + threadIdx.x;
    if (e < E) atomicAdd(&cnt[row[e]], 1);
}

// phase A: per-block (1024 counts) sums
__global__ __launch_bounds__(256) void scanA_kernel(const int* __restrict__ cnt,
                                                    int* __restrict__ blockSum, int N) {
    int t = threadIdx.x;
    int i0 = blockIdx.x * 1024 + t * 4;
    int s = 0;
    if (i0 + 3 < N) {
        int4 v = ((const int4*)cnt)[i0 >> 2];
        s = v.x + v.y + v.z + v.w;
    } else {
        #pragma unroll
        for (int j = 0; j < 4; ++j) if (i0 + j < N) s += cnt[i0 + j];
    }
    #pragma unroll
    for (int off = 32; off > 0; off >>= 1) s += __shfl_down(s, off, 64);
    __shared__ int ws[4];
    if ((t & 63) == 0) ws[t >> 6] = s;
    __syncthreads();
    if (t == 0) blockSum[blockIdx.x] = ws[0] + ws[1] + ws[2] + ws[3];
}

// phase B: single block scans <=1024 block sums -> exclusive block offsets
__global__ __launch_bounds__(1024) void scanB_kernel(const int* __restrict__ blockSum,
                                                     int* __restrict__ blockOff,
                                                     int nb, int* __restrict__ rowptr,
                                                     int N, int E) {
    __shared__ int sh[1024];
    int t = threadIdx.x;
    int v = (t < nb) ? blockSum[t] : 0;
    sh[t] = v;
    __syncthreads();
    #pragma unroll
    for (int off = 1; off < 1024; off <<= 1) {
        int add = (t >= off) ? sh[t - off] : 0;
        __syncthreads();
        sh[t] += add;
        __syncthreads();
    }
    if (t < nb) blockOff[t] = sh[t] - v;
    if (t == 0) rowptr[N] = E;
}

// phase C: rescan 1024 counts per block, add block offset -> rowptr & wptr
__global__ __launch_bounds__(256) void scanC_kernel(const int* __restrict__ cnt,
                                                    const int* __restrict__ blockOff,
                                                    int* __restrict__ rowptr,
                                                    int* __restrict__ wptr, int N) {
    int t = threadIdx.x;
    int i0 = blockIdx.x * 1024 + t * 4;
    int v0 = 0, v1 = 0, v2 = 0, v3 = 0;
    if (i0 + 3 < N) {
        int4 v = ((const int4*)cnt)[i0 >> 2];
        v0 = v.x; v1 = v.y; v2 = v.z; v3 = v.w;
    } else {
        if (i0 + 0 < N) v0 = cnt[i0 + 0];
        if (i0 + 1 < N) v1 = cnt[i0 + 1];
        if (i0 + 2 < N) v2 = cnt[i0 + 2];
        if (i0 + 3 < N) v3 = cnt[i0 + 3];
    }
    int s = v0 + v1 + v2 + v3;
    int lane = t & 63, wv = t >> 6;
    int inc = s;
    #pragma unroll
    for (int off = 1; off < 64; off <<= 1) {
        int up = __shfl_up(inc, off, 64);
        if (lane >= off) inc += up;
    }
    __shared__ int wsum[4];
    if (lane == 63) wsum[wv] = inc;
    __syncthreads();
    int woff = 0;
    #pragma unroll
    for (int j = 0; j < 4; ++j) woff += (j < wv) ? wsum[j] : 0;
    int excl = blockOff[blockIdx.x] + woff + inc - s;
    if (i0 + 0 < N) { rowptr[i0 + 0] = excl;                  wptr[i0 + 0] = excl; }
    if (i0 + 1 < N) { rowptr[i0 + 1] = excl + v0;             wptr[i0 + 1] = excl + v0; }
    if (i0 + 2 < N) { rowptr[i0 + 2] = excl + v0 + v1;        wptr[i0 + 2] = excl + v0 + v1; }
    if (i0 + 3 < N) { rowptr[i0 + 3] = excl + v0 + v1 + v2;   wptr[i0 + 3] = excl + v0 + v1 + v2; }
}

__global__ __launch_bounds__(256) void scatter_kernel(const int* __restrict__ row,
                                                      const int* __restrict__ col,
                                                      const float* __restrict__ w,
                                                      int* __restrict__ wptr,
                                                      int2* __restrict__ pairs, int E) {
    int e = blockIdx.x * 256 + threadIdx.x;
    if (e >= E) return;
    int pos = atomicAdd(&wptr[row[e]], 1);
    pairs[pos] = make_int2(col[e], __float_as_int(w[e]));
}

// ---------------------------------------------------------------------------
// CSR SpMM, bf16 gather operand: one wave per row, lane l covers feats 2l,2l+1.
// 8-edge preload: 8 pair-loads + 8 gathers in flight before the FMA block.
// out[r] = (bias? bias : 0) + sum_i w_i * H[col_i]
// ---------------------------------------------------------------------------
__global__ __launch_bounds__(256) void spmm_csr_kernel(const int* __restrict__ rowptr,
                                                       const int2* __restrict__ pairs,
                                                       const unsigned int* __restrict__ Hb,
                                                       const float* __restrict__ bias,
                                                       float* __restrict__ out, int N) {
    int r = blockIdx.x * 4 + (threadIdx.x >> 6);
    if (r >= N) return;
    int l = threadIdx.x & 63;
    float2 acc = bias ? ((const float2*)bias)[l] : make_float2(0.f, 0.f);
    int i = rowptr[r], end = rowptr[r + 1];

    for (; i + 8 <= end; i += 8) {
        int2 p[8];
        #pragma unroll
        for (int j = 0; j < 8; ++j) p[j] = pairs[i + j];
        unsigned int g[8];
        #pragma unroll
        for (int j = 0; j < 8; ++j) g[j] = Hb[(size_t)p[j].x * FU + l];
        #pragma unroll
        for (int j = 0; j < 8; ++j) {
            float wt = __int_as_float(p[j].y);
            acc.x = fmaf(wt, __uint_as_float(g[j] << 16), acc.x);
            acc.y = fmaf(wt, __uint_as_float(g[j] & 0xffff0000u), acc.y);
        }
    }
    if (i + 4 <= end) {
        int2 p[4];
        #pragma unroll
        for (int j = 0; j < 4; ++j) p[j] = pairs[i + j];
        unsigned int g[4];
        #pragma unroll
        for (int j = 0; j < 4; ++j) g[j] = Hb[(size_t)p[j].x * FU + l];
        #pragma unroll
        for (int j = 0; j < 4; ++j) {
            float wt = __int_as_float(p[j].y);
            acc.x = fmaf(wt, __uint_as_float(g[j] << 16), acc.x);
            acc.y = fmaf(wt, __uint_as_float(g[j] & 0xffff0000u), acc.y);
        }
        i += 4;
    }
    for (; i < end; ++i) {
        int2 p = pairs[i];
        unsigned int g = Hb[(size_t)p.x * FU + l];
        float wt = __int_as_float(p.y);
        acc.x = fmaf(wt, __uint_as_float(g << 16), acc.x);
        acc.y = fmaf(wt, __uint_as_float(g & 0xffff0000u), acc.y);
    }
    ((float2*)out)[(size_t)r * 64 + l] = acc;
}

// ---------------------------------------------------------------------------
// BN batch statistics: per-feature sum and sumsq over nodes (fp32 input).
// ---------------------------------------------------------------------------
__global__ __launch_bounds__(256) void bnstats_kernel(const float* __restrict__ H,
                                                      float* __restrict__ sums,
                                                      int nNodes) {
    int f = threadIdx.x & 127;
    int g = threadIdx.x >> 7;  // 0..1
    int stride = gridDim.x * 2;
    float s = 0.f, sq = 0.f;
    for (int n = blockIdx.x * 2 + g; n < nNodes; n += stride) {
        float v = H[(size_t)n * F + f];
        s += v;
        sq = fmaf(v, v, sq);
    }
    __shared__ float red[256];
    red[threadIdx.x] = s;
    __syncthreads();
    float sfull = 0.f;
    if (g == 0) sfull = red[f] + red[f + 128];
    __syncthreads();
    red[threadIdx.x] = sq;
    __syncthreads();
    if (g == 0) {
        float sqfull = red[f] + red[f + 128];
        atomicAdd(&sums[f], sfull);
        atomicAdd(&sums[128 + f], sqfull);
    }
}

// Fold mean/var/gamma/beta into per-feature scale a and shift c.
// Note: layer-1 bias b1 cancels exactly in BN (mean subtraction) -> unused.
__global__ void bnfinal_kernel(const float* __restrict__ sums,
                               const float* __restrict__ gamma,
                               const float* __restrict__ beta,
                               float* __restrict__ ac, float invN) {
    int f = threadIdx.x;
    float mean = sums[f] * invN;
    float var = sums[128 + f] * invN - mean * mean;
    float a = gamma[f] * rsqrtf(var + 1e-5f);
    ac[f] = a;
    ac[128 + f] = beta[f] - mean * a;
}

extern "C" void kernel_launch(void* const* d_in, const int* in_sizes, int n_in,
                              void* d_out, int out_size, void* d_ws, size_t ws_size,
                              hipStream_t stream) {
    const float* x    = (const float*)d_in[0];
    const int*   erow = (const int*)d_in[1];
    const int*   ecol = (const int*)d_in[2];
    const float* ew   = (const float*)d_in[3];
    const float* W1   = (const float*)d_in[4];
    // d_in[5] = b1: unused — cancels exactly under BatchNorm mean subtraction.
    const float* W2   = (const float*)d_in[6];
    const float* b2   = (const float*)d_in[7];
    const float* gmm  = (const float*)d_in[8];
    const float* beta = (const float*)d_in[9];
    float* out = (float*)d_out;

    const int N = in_sizes[0] / F;   // 100000
    const int E = in_sizes[1];       // 1600000

    // ---- workspace carve-up (all offsets keep 16-B alignment) ----
    float*        buf1   = (float*)d_ws;                    // N*F fp32: spmm1 out
    unsigned int* Hb     = (unsigned int*)(buf1 + (size_t)N * F); // N*FU: bf16 H
    float*        stats  = (float*)(Hb + (size_t)N * FU);   // 256
    float*        ac     = stats + 256;                     // 256
    int*          cnt    = (int*)(ac + 256);                // N
    int*          rowptr = cnt + N;                         // N+2 (pad for align)
    int*          wptr   = rowptr + N + 2;                  // N
    int*          blockSum = wptr + N;                      // 1024
    int*          blockOff = blockSum + 1024;               // 1024
    int2*         pairs  = (int2*)(blockOff + 1024);        // E

    const int gemmGrid = (N + 31) / 32;
    const int eGrid    = (E + 255) / 256;
    const int nb       = (N + 1023) / 1024;  // scan blocks
    const int spmmGrid = (N + 3) / 4;

    hipMemsetAsync(stats, 0, 256 * sizeof(float), stream);
    hipMemsetAsync(cnt, 0, (size_t)N * sizeof(int), stream);

    // ---- build CSR (shared by both SpMM layers) ----
    count_kernel<<<eGrid, 256, 0, stream>>>(erow, cnt, E);
    scanA_kernel<<<nb, 256, 0, stream>>>(cnt, blockSum, N);
    scanB_kernel<<<1, 1024, 0, stream>>>(blockSum, blockOff, nb, rowptr, N, E);
    scanC_kernel<<<nb, 256, 0, stream>>>(cnt, blockOff, rowptr, wptr, N);
    scatter_kernel<<<eGrid, 256, 0, stream>>>(erow, ecol, ew, wptr, pairs, E);

    // Layer 1: Hb = bf16(x @ W1) ; buf1 = A @ Hb
    gemm_kernel<false><<<gemmGrid, 256, 0, stream>>>(x, W1, nullptr, Hb, N);
    spmm_csr_kernel<<<spmmGrid, 256, 0, stream>>>(rowptr, pairs, Hb, nullptr, buf1, N);
    // BN stats + fold
    bnstats_kernel<<<400, 256, 0, stream>>>(buf1, stats, N);
    bnfinal_kernel<<<1, 128, 0, stream>>>(stats, gmm, beta, ac, 1.0f / (float)N);
    // Layer 2: Hb = bf16(relu(bn(buf1)) @ W2) ; out = A @ Hb + b2
    gemm_kernel<true><<<gemmGrid, 256, 0, stream>>>(buf1, W2, ac, Hb, N);
    spmm_csr_kernel<<<spmmGrid, 256, 0, stream>>>(rowptr, pairs, Hb, b2, out, N);
}